// Round 12
// baseline (255.747 us; speedup 1.0000x reference)
//
#include <hip/hip_runtime.h>
#include <hip/hip_bf16.h>
#include <math.h>

#define BATCH   2
#define SEQLEN  1024
#define DMODEL  1024
#define DINNER  2048
#define DSTATE  16
#define DTRANK  64
#define XPAD    128             // padded x_dbl row stride (96 -> 128)
#define MROWS   (BATCH*SEQLEN)  // 2048
#define NSEG    8
#define SEGLEN  (SEQLEN/NSEG)   // 128
#define XP_SPLIT  8

typedef float    f32x4  __attribute__((ext_vector_type(4)));
typedef _Float16 f16x8  __attribute__((ext_vector_type(8)));
typedef _Float16 f16x4  __attribute__((ext_vector_type(4)));

// ---------------------------------------------------------------------------
// In-staging causal depthwise conv (k=4) + bias + SiLU for one 8-wide d-chunk
// of token-row mrow, computed from xz16 [MROWS, 2*DINNER] x-half.
// ---------------------------------------------------------------------------
__device__ __forceinline__ f16x8 conv_row8(
    const _Float16* __restrict__ xz, int mrow, int dbase,
    const float* __restrict__ conv_w, const float* __restrict__ conv_b)
{
  const int l = mrow & (SEQLEN - 1);
  const _Float16* base = xz + (size_t)mrow * (2 * DINNER) + dbase;
  float acc[8];
#pragma unroll
  for (int j = 0; j < 8; ++j) acc[j] = conv_b[dbase + j];
#pragma unroll
  for (int k = 0; k < 4; ++k) {
    if (l + k - 3 >= 0) {
      f16x8 xh = *(const f16x8*)(base + (ptrdiff_t)(k - 3) * (2 * DINNER));
#pragma unroll
      for (int j = 0; j < 8; ++j)
        acc[j] = fmaf((float)xh[j], conv_w[(dbase + j) * 4 + k], acc[j]);
    }
  }
  f16x8 r;
#pragma unroll
  for (int j = 0; j < 8; ++j) {
    float s = acc[j];
    r[j] = (_Float16)(s / (1.f + __expf(-s)));
  }
  return r;
}

// ---------------------------------------------------------------------------
// Pipelined fp16 MFMA GEMM, 64x128 tile, BK=64.
// Line-coalesced staging, reg-prefetch, LDS double-buffer, 1 barrier/iter.
// CONVA: A operand is xz16; staging computes conv+SiLU on the fly (x_proj).
// EPI 0: fp32 store (+zstride partials)  2: softplus(acc+2*bias) -> f16 C16
// ---------------------------------------------------------------------------
template<int EPI, bool CONVA>
__global__ __launch_bounds__(256) void pgemm64(
    const _Float16* __restrict__ A, int lda,
    const _Float16* __restrict__ W, int ldw,
    float* __restrict__ C, int ldc, int K,
    const float* __restrict__ bias, _Float16* __restrict__ C16, size_t zstride,
    const float* __restrict__ conv_w, const float* __restrict__ conv_b)
{
  constexpr int APS = 520;    // A kb-plane stride (halves): 64*8 + 8 pad
  constexpr int BPS = 1032;   // B kb-plane stride: 128*8 + 8 pad
  __shared__ _Float16 As[2][8 * APS];
  __shared__ _Float16 Bs[2][8 * BPS];

  const int t  = threadIdx.x;
  const int m0 = blockIdx.y * 64, n0 = blockIdx.x * 128;
  const int kchunk = K / gridDim.z;
  const int kbeg = blockIdx.z * kchunk;
  const int nIter = kchunk / 64;

  const int kb = t & 7;
  const int r0 = t >> 3;
  const _Float16* gA = A + (size_t)(m0 + r0) * lda + kbeg + kb * 8;
  const _Float16* gB = W + (size_t)(n0 + r0) * ldw + kbeg + kb * 8;
  const size_t a32 = (size_t)32 * lda;
  const size_t b32 = (size_t)32 * ldw;
  const int aoff = kb * APS + r0 * 8;
  const int boff = kb * BPS + r0 * 8;
  int kcur = kbeg;

  {
    f16x8 a0, a1;
    if constexpr (CONVA) {
      a0 = conv_row8(A, m0 + r0,      kcur + kb * 8, conv_w, conv_b);
      a1 = conv_row8(A, m0 + r0 + 32, kcur + kb * 8, conv_w, conv_b);
    } else {
      a0 = *(const f16x8*)(gA);
      a1 = *(const f16x8*)(gA + a32);
    }
    f16x8 b0 = *(const f16x8*)(gB);
    f16x8 b1 = *(const f16x8*)(gB + b32);
    f16x8 b2 = *(const f16x8*)(gB + 2 * b32);
    f16x8 b3 = *(const f16x8*)(gB + 3 * b32);
    gA += 64; gB += 64; kcur += 64;
    *(f16x8*)&As[0][aoff]       = a0;
    *(f16x8*)&As[0][aoff + 256] = a1;
    *(f16x8*)&Bs[0][boff]       = b0;
    *(f16x8*)&Bs[0][boff + 256] = b1;
    *(f16x8*)&Bs[0][boff + 512] = b2;
    *(f16x8*)&Bs[0][boff + 768] = b3;
  }

  const int lane = t & 63, wvi = t >> 6;
  const int wn = wvi * 32;
  const int lm = lane & 15, lk = lane >> 4;

  f32x4 acc[4][2] = {};

  for (int it = 0; it < nIter; ++it) {
    __syncthreads();
    const bool more = (it + 1 < nIter);
    f16x8 a0, a1, b0, b1, b2, b3;
    if (more) {
      if constexpr (CONVA) {
        a0 = conv_row8(A, m0 + r0,      kcur + kb * 8, conv_w, conv_b);
        a1 = conv_row8(A, m0 + r0 + 32, kcur + kb * 8, conv_w, conv_b);
      } else {
        a0 = *(const f16x8*)(gA);
        a1 = *(const f16x8*)(gA + a32);
      }
      b0 = *(const f16x8*)(gB);
      b1 = *(const f16x8*)(gB + b32);
      b2 = *(const f16x8*)(gB + 2 * b32);
      b3 = *(const f16x8*)(gB + 3 * b32);
      gA += 64; gB += 64; kcur += 64;
    }
    const int cb = it & 1;
#pragma unroll
    for (int s = 0; s < 2; ++s) {
      f16x8 av[4], bv[2];
#pragma unroll
      for (int i = 0; i < 4; ++i)
        av[i] = *(const f16x8*)&As[cb][(s * 4 + lk) * APS + (i * 16 + lm) * 8];
#pragma unroll
      for (int j = 0; j < 2; ++j)
        bv[j] = *(const f16x8*)&Bs[cb][(s * 4 + lk) * BPS + (wn + j * 16 + lm) * 8];
#pragma unroll
      for (int i = 0; i < 4; ++i)
#pragma unroll
        for (int j = 0; j < 2; ++j)
          acc[i][j] = __builtin_amdgcn_mfma_f32_16x16x32_f16(av[i], bv[j], acc[i][j], 0, 0, 0);
    }
    if (more) {
      const int nb = (it + 1) & 1;
      *(f16x8*)&As[nb][aoff]       = a0;
      *(f16x8*)&As[nb][aoff + 256] = a1;
      *(f16x8*)&Bs[nb][boff]       = b0;
      *(f16x8*)&Bs[nb][boff + 256] = b1;
      *(f16x8*)&Bs[nb][boff + 512] = b2;
      *(f16x8*)&Bs[nb][boff + 768] = b3;
    }
  }

  float* Cz = C + (size_t)blockIdx.z * zstride;
#pragma unroll
  for (int i = 0; i < 4; ++i) {
    const int mrow = m0 + i * 16 + lk * 4;
#pragma unroll
    for (int j = 0; j < 2; ++j) {
      const int col = n0 + wn + j * 16 + lm;
#pragma unroll
      for (int r = 0; r < 4; ++r) {
        float v = acc[i][j][r];
        size_t off = (size_t)(mrow + r) * ldc + col;
        if constexpr (EPI == 0) {
          Cz[off] = v;
        } else {  // EPI == 2: softplus -> f16
          float x = v + 2.f * bias[col];
          float sp = (x > 20.f) ? x : log1pf(__expf(x));
          C16[off] = (_Float16)sp;
        }
      }
    }
  }
}

// ---------------------------------------------------------------------------
// Pipelined fp16 MFMA GEMM, 128x128 tile, BK=64, 4 waves 2x2 (64x64/wave).
// EPI 0: fp32 store   4: f16 store
// ---------------------------------------------------------------------------
template<int EPI>
__global__ __launch_bounds__(256) void pgemm128(
    const _Float16* __restrict__ A, int lda,
    const _Float16* __restrict__ W, int ldw,
    float* __restrict__ C, int ldc, int K,
    _Float16* __restrict__ C16)
{
  constexpr int PS = 1032;            // plane stride halves: 128*8 + 8 pad
  __shared__ _Float16 As[2][8 * PS];  // 33 KB
  __shared__ _Float16 Bs[2][8 * PS];  // 33 KB

  const int t  = threadIdx.x;
  const int m0 = blockIdx.y * 128, n0 = blockIdx.x * 128;
  const int nIter = K / 64;

  const int kb = t & 7;
  const int r0 = t >> 3;
  const _Float16* gA = A + (size_t)(m0 + r0) * lda + kb * 8;
  const _Float16* gB = W + (size_t)(n0 + r0) * ldw + kb * 8;
  const size_t a32 = (size_t)32 * lda;
  const size_t b32 = (size_t)32 * ldw;
  const int soff = kb * PS + r0 * 8;

  {
    f16x8 ar[4], br[4];
#pragma unroll
    for (int j = 0; j < 4; ++j) {
      ar[j] = *(const f16x8*)(gA + j * a32);
      br[j] = *(const f16x8*)(gB + j * b32);
    }
    gA += 64; gB += 64;
#pragma unroll
    for (int j = 0; j < 4; ++j) {
      *(f16x8*)&As[0][soff + j * 256] = ar[j];
      *(f16x8*)&Bs[0][soff + j * 256] = br[j];
    }
  }

  const int lane = t & 63, wvi = t >> 6;
  const int wm = (wvi >> 1) * 64, wn = (wvi & 1) * 64;
  const int lm = lane & 15, lk = lane >> 4;

  f32x4 acc[4][4] = {};

  for (int it = 0; it < nIter; ++it) {
    __syncthreads();
    const bool more = (it + 1 < nIter);
    f16x8 ar[4], br[4];
    if (more) {
#pragma unroll
      for (int j = 0; j < 4; ++j) {
        ar[j] = *(const f16x8*)(gA + j * a32);
        br[j] = *(const f16x8*)(gB + j * b32);
      }
      gA += 64; gB += 64;
    }
    const int cb = it & 1;
#pragma unroll
    for (int s = 0; s < 2; ++s) {
      f16x8 av[4], bv[4];
#pragma unroll
      for (int i = 0; i < 4; ++i)
        av[i] = *(const f16x8*)&As[cb][(s * 4 + lk) * PS + (wm + i * 16 + lm) * 8];
#pragma unroll
      for (int j = 0; j < 4; ++j)
        bv[j] = *(const f16x8*)&Bs[cb][(s * 4 + lk) * PS + (wn + j * 16 + lm) * 8];
#pragma unroll
      for (int i = 0; i < 4; ++i)
#pragma unroll
        for (int j = 0; j < 4; ++j)
          acc[i][j] = __builtin_amdgcn_mfma_f32_16x16x32_f16(av[i], bv[j], acc[i][j], 0, 0, 0);
    }
    if (more) {
      const int nb = (it + 1) & 1;
#pragma unroll
      for (int j = 0; j < 4; ++j) {
        *(f16x8*)&As[nb][soff + j * 256] = ar[j];
        *(f16x8*)&Bs[nb][soff + j * 256] = br[j];
      }
    }
  }

#pragma unroll
  for (int i = 0; i < 4; ++i) {
    const int mrow = m0 + wm + i * 16 + lk * 4;
#pragma unroll
    for (int j = 0; j < 4; ++j) {
      const int col = n0 + wn + j * 16 + lm;
#pragma unroll
      for (int r = 0; r < 4; ++r) {
        float v = acc[i][j][r];
        size_t off = (size_t)(mrow + r) * ldc + col;
        if constexpr (EPI == 0) {
          C[off] = v;
        } else {  // EPI == 4
          C16[off] = (_Float16)v;
        }
      }
    }
  }
}

// ---------------------------------------------------------------------------
// Fused fp32 -> fp16 conversion of all weights + hidden (one launch).
// ---------------------------------------------------------------------------
#define R0 (MROWS * DMODEL / 4)            // hidden:      524288
#define R1 (2 * DINNER * DMODEL / 4)       // in_proj_w:  1048576
#define R2 (DMODEL * DINNER / 4)           // out_proj_w:  524288
#define R3 (DINNER * DTRANK / 4)           // dt_proj_w:    32768
#define R4 (XPAD * DINNER / 4)             // x_proj_w pad: 65536
#define F2H_TOTAL (R0 + R1 + R2 + R3 + R4)

__global__ __launch_bounds__(256) void f2h_all(
    const float* __restrict__ hid, const float* __restrict__ w_in,
    const float* __restrict__ w_out, const float* __restrict__ w_dt,
    const float* __restrict__ w_xp,
    _Float16* __restrict__ hid16, _Float16* __restrict__ w_in16,
    _Float16* __restrict__ w_out16, _Float16* __restrict__ w_dt16,
    _Float16* __restrict__ w_xp16)
{
  int i = blockIdx.x * 256 + threadIdx.x;
  const float* src; _Float16* dst; int off;
  if (i < R0)                     { src = hid;   dst = hid16;   off = i; }
  else if (i < R0+R1)             { src = w_in;  dst = w_in16;  off = i - R0; }
  else if (i < R0+R1+R2)          { src = w_out; dst = w_out16; off = i - (R0+R1); }
  else if (i < R0+R1+R2+R3)       { src = w_dt;  dst = w_dt16;  off = i - (R0+R1+R2); }
  else if (i < F2H_TOTAL) {
    off = i - (R0+R1+R2+R3);
    int r = (off * 4) >> 11;                 // row of padded [128, 2048]
    f16x4 h = {0, 0, 0, 0};
    if (r < 96) {
      float4 v = ((const float4*)w_xp)[off];
      h = (f16x4){(_Float16)v.x, (_Float16)v.y, (_Float16)v.z, (_Float16)v.w};
    }
    ((f16x4*)w_xp16)[off] = h;
    return;
  } else return;
  float4 v = ((const float4*)src)[off];
  ((f16x4*)dst)[off] = (f16x4){(_Float16)v.x, (_Float16)v.y, (_Float16)v.z, (_Float16)v.w};
}

// ---------------------------------------------------------------------------
// Reduce x_proj split-K partials -> xdbl32 [2048,128] + f16 dt-cols [2048,64]
// ---------------------------------------------------------------------------
__global__ __launch_bounds__(256) void reduce_xdbl(
    const float* __restrict__ part,       // [XP_SPLIT][2048*128]
    float* __restrict__ xdbl32, _Float16* __restrict__ xdbl16)
{
  int i = blockIdx.x * 256 + threadIdx.x;          // float4 units, < 65536
  f32x4 s = ((const f32x4*)part)[i];
#pragma unroll
  for (int z = 1; z < XP_SPLIT; ++z)
    s += ((const f32x4*)part)[(size_t)z * (MROWS * XPAD / 4) + i];
  ((f32x4*)xdbl32)[i] = s;
  int col4 = (i & 31) * 4;
  if (col4 < DTRANK) {
    int row = i >> 5;
    *(f16x4*)&xdbl16[(size_t)row * DTRANK + col4] =
        (f16x4){(_Float16)s.x, (_Float16)s.y, (_Float16)s.z, (_Float16)s.w};
  }
}

// ---------------------------------------------------------------------------
// Selective scan, two-pass sequence-split; u computed in-staging from xz16
// (conv+SiLU fused; conv weights hoisted to registers, off the serial path).
// ---------------------------------------------------------------------------
__device__ __forceinline__ float row_sum16(float x) {
  int v = __builtin_bit_cast(int, x);
  x += __builtin_bit_cast(float, __builtin_amdgcn_update_dpp(0, v, 0x128, 0xF, 0xF, true)); // row_ror:8
  v = __builtin_bit_cast(int, x);
  x += __builtin_bit_cast(float, __builtin_amdgcn_update_dpp(0, v, 0x124, 0xF, 0xF, true)); // row_ror:4
  v = __builtin_bit_cast(int, x);
  x += __builtin_bit_cast(float, __builtin_amdgcn_update_dpp(0, v, 0x4E, 0xF, 0xF, true));  // quad xor2
  v = __builtin_bit_cast(int, x);
  x += __builtin_bit_cast(float, __builtin_amdgcn_update_dpp(0, v, 0xB1, 0xF, 0xF, true));  // quad xor1
  return x;
}

__global__ __launch_bounds__(256) void scan_part1(
    const _Float16* __restrict__ delta16,
    const _Float16* __restrict__ xz16,
    const float* __restrict__ x_dbl,
    const float* __restrict__ A_log,
    const float* __restrict__ conv_w,
    const float* __restrict__ conv_b,
    float* __restrict__ pbuf, float* __restrict__ ebuf)
{
  const int t = threadIdx.x;
  const int c = t >> 4, n = t & 15;
  const int bb = blockIdx.x;
  const int seg = bb >> 8;
  const int r = bb & 255;
  const int b = r >> 7;
  const int d_base = (r & 127) * 16;

  const float A_dn = -__expf(A_log[(d_base + c) * DSTATE + n]);
  float s = 0.f, p = 1.f;

  __shared__ __align__(16) float dl[16 * 68];
  __shared__ __align__(16) float ul[16 * 68];
  __shared__ __align__(16) float Bl[16 * 68];

  const int i_st = t >> 2;
  const int cc = (t & 3) * 4;

  float cw[4][4], cb4[4];
#pragma unroll
  for (int j = 0; j < 4; ++j) {
    cb4[j] = conv_b[d_base + cc + j];
#pragma unroll
    for (int k = 0; k < 4; ++k) cw[j][k] = conv_w[(d_base + cc + j) * 4 + k];
  }

  for (int l0 = seg * SEGLEN; l0 < seg * SEGLEN + SEGLEN; l0 += 64) {
    const int row = b * SEQLEN + l0 + i_st;
    const int l = l0 + i_st;
    {
      f16x4  dh = *(const f16x4*)&delta16[(size_t)row * DINNER + d_base + cc];
      float4 Bv = *(const float4*)&x_dbl[(size_t)row * XPAD + DTRANK + cc];
      float ua[4] = {cb4[0], cb4[1], cb4[2], cb4[3]};
#pragma unroll
      for (int k = 0; k < 4; ++k) {
        if (l + k - 3 >= 0) {
          f16x4 xh = *(const f16x4*)&xz16[(size_t)(row + k - 3) * (2 * DINNER) + d_base + cc];
#pragma unroll
          for (int j = 0; j < 4; ++j) ua[j] = fmaf((float)xh[j], cw[j][k], ua[j]);
        }
      }
      dl[(cc+0)*68 + i_st] = (float)dh[0]; dl[(cc+1)*68 + i_st] = (float)dh[1];
      dl[(cc+2)*68 + i_st] = (float)dh[2]; dl[(cc+3)*68 + i_st] = (float)dh[3];
#pragma unroll
      for (int j = 0; j < 4; ++j) {
        float us = ua[j];
        ul[(cc+j)*68 + i_st] = us / (1.f + __expf(-us));
      }
      Bl[(cc+0)*68 + i_st] = Bv.x; Bl[(cc+1)*68 + i_st] = Bv.y;
      Bl[(cc+2)*68 + i_st] = Bv.z; Bl[(cc+3)*68 + i_st] = Bv.w;
    }
    __syncthreads();
#pragma unroll
    for (int i0 = 0; i0 < 64; i0 += 4) {
      f32x4 dv4 = *(const f32x4*)&dl[c * 68 + i0];
      f32x4 uv4 = *(const f32x4*)&ul[c * 68 + i0];
      f32x4 Bv4 = *(const f32x4*)&Bl[n * 68 + i0];
#pragma unroll
      for (int rr = 0; rr < 4; ++rr) {
        float dA = __expf(dv4[rr] * A_dn);
        s = fmaf(dA, s, dv4[rr] * Bv4[rr] * uv4[rr]);
        p *= dA;
      }
    }
    __syncthreads();
  }
  const int peIdx = (r * NSEG + seg) * 256 + t;
  pbuf[peIdx] = p;
  ebuf[peIdx] = s;
}

__global__ __launch_bounds__(256) void scan_part2(
    const _Float16* __restrict__ delta16,
    const _Float16* __restrict__ xz16,   // x at cols [0,2048), z at [2048,4096)
    const float* __restrict__ x_dbl,
    const float* __restrict__ A_log,
    const float* __restrict__ Dp,
    const float* __restrict__ conv_w,
    const float* __restrict__ conv_b,
    const float* __restrict__ pbuf,
    const float* __restrict__ ebuf,
    _Float16* __restrict__ y16)
{
  const int t = threadIdx.x;
  const int c = t >> 4, n = t & 15;
  const int bb = blockIdx.x;
  const int seg = bb >> 8;
  const int r = bb & 255;
  const int b = r >> 7;
  const int d_base = (r & 127) * 16;

  const float A_dn = -__expf(A_log[(d_base + c) * DSTATE + n]);

  float s = 0.f;
  {
    const int base = r * NSEG * 256 + t;
    for (int k = 0; k < seg; ++k)
      s = fmaf(pbuf[base + k * 256], s, ebuf[base + k * 256]);
  }

  __shared__ __align__(16) float dl[16 * 68];
  __shared__ __align__(16) float ul[16 * 68];
  __shared__ __align__(16) float Bl[16 * 68];
  __shared__ __align__(16) float Cl[16 * 68];
  __shared__ __align__(16) float yl[16 * 68];
  __shared__ __align__(16) float z_s[64 * 16];
  __shared__ float Dp_s[16];

  if (t < 16) Dp_s[t] = Dp[d_base + t];

  const int i_st = t >> 2;
  const int cc = (t & 3) * 4;

  float cw[4][4], cb4[4];
#pragma unroll
  for (int j = 0; j < 4; ++j) {
    cb4[j] = conv_b[d_base + cc + j];
#pragma unroll
    for (int k = 0; k < 4; ++k) cw[j][k] = conv_w[(d_base + cc + j) * 4 + k];
  }

  for (int l0 = seg * SEGLEN; l0 < seg * SEGLEN + SEGLEN; l0 += 64) {
    const int row = b * SEQLEN + l0 + i_st;
    const int l = l0 + i_st;
    {
      f16x4  dh = *(const f16x4*)&delta16[(size_t)row * DINNER + d_base + cc];
      float4 Bv = *(const float4*)&x_dbl[(size_t)row * XPAD + DTRANK + cc];
      float4 Cv = *(const float4*)&x_dbl[(size_t)row * XPAD + DTRANK + DSTATE + cc];
      f16x4  zh = *(const f16x4*)&xz16[(size_t)row * (2 * DINNER) + DINNER + d_base + cc];
      float ua[4] = {cb4[0], cb4[1], cb4[2], cb4[3]};
#pragma unroll
      for (int k = 0; k < 4; ++k) {
        if (l + k - 3 >= 0) {
          f16x4 xh = *(const f16x4*)&xz16[(size_t)(row + k - 3) * (2 * DINNER) + d_base + cc];
#pragma unroll
          for (int j = 0; j < 4; ++j) ua[j] = fmaf((float)xh[j], cw[j][k], ua[j]);
        }
      }
      dl[(cc+0)*68 + i_st] = (float)dh[0]; dl[(cc+1)*68 + i_st] = (float)dh[1];
      dl[(cc+2)*68 + i_st] = (float)dh[2]; dl[(cc+3)*68 + i_st] = (float)dh[3];
#pragma unroll
      for (int j = 0; j < 4; ++j) {
        float us = ua[j];
        ul[(cc+j)*68 + i_st] = us / (1.f + __expf(-us));
      }
      Bl[(cc+0)*68 + i_st] = Bv.x; Bl[(cc+1)*68 + i_st] = Bv.y;
      Bl[(cc+2)*68 + i_st] = Bv.z; Bl[(cc+3)*68 + i_st] = Bv.w;
      Cl[(cc+0)*68 + i_st] = Cv.x; Cl[(cc+1)*68 + i_st] = Cv.y;
      Cl[(cc+2)*68 + i_st] = Cv.z; Cl[(cc+3)*68 + i_st] = Cv.w;
      float4 zv = make_float4((float)zh[0], (float)zh[1], (float)zh[2], (float)zh[3]);
      *(float4*)&z_s[t * 4] = zv;
    }
    __syncthreads();

#pragma unroll
    for (int i0 = 0; i0 < 64; i0 += 4) {
      f32x4 dv4 = *(const f32x4*)&dl[c * 68 + i0];
      f32x4 uv4 = *(const f32x4*)&ul[c * 68 + i0];
      f32x4 Bv4 = *(const f32x4*)&Bl[n * 68 + i0];
      f32x4 Cv4 = *(const f32x4*)&Cl[n * 68 + i0];
      f32x4 py;
#pragma unroll
      for (int rr = 0; rr < 4; ++rr) {
        float dA = __expf(dv4[rr] * A_dn);
        s = fmaf(dA, s, dv4[rr] * Bv4[rr] * uv4[rr]);
        py[rr] = row_sum16(s * Cv4[rr]);
      }
      if (n == 0) *(f32x4*)&yl[c * 68 + i0] = py;
    }
    __syncthreads();

#pragma unroll
    for (int k = 0; k < 4; ++k) {
      int o = t + 256 * k;
      int i = o >> 4, c2 = o & 15;
      float ssum = yl[c2 * 68 + i];
      float uv = ul[c2 * 68 + i];
      float zv = z_s[o];
      float yv = fmaf(uv, Dp_s[c2], ssum);
      yv *= zv / (1.f + __expf(-zv));
      y16[(size_t)(b * SEQLEN + l0 + i) * DINNER + d_base + c2] = (_Float16)yv;
    }
    __syncthreads();
  }
}

// ---------------------------------------------------------------------------
extern "C" void kernel_launch(void* const* d_in, const int* in_sizes, int n_in,
                              void* d_out, int out_size, void* d_ws, size_t ws_size,
                              hipStream_t stream)
{
  const float* hidden     = (const float*)d_in[0];
  const float* in_proj_w  = (const float*)d_in[1];
  const float* conv_w     = (const float*)d_in[2];
  const float* conv_b     = (const float*)d_in[3];
  const float* x_proj_w   = (const float*)d_in[4];
  const float* dt_proj_w  = (const float*)d_in[5];
  const float* dt_proj_b  = (const float*)d_in[6];
  const float* A_log      = (const float*)d_in[7];
  const float* Dp         = (const float*)d_in[8];
  const float* out_proj_w = (const float*)d_in[9];
  float* out = (float*)d_out;

  char* p = (char*)d_ws;
  _Float16* xz16    = (_Float16*)p;  p += (size_t)MROWS * 2 * DINNER * 2;  // 16.8MB
  float*    xdbl32  = (float*)p;     p += (size_t)MROWS * XPAD * 4;        // 1.05MB
  _Float16* delta16 = (_Float16*)p;  p += (size_t)MROWS * DINNER * 2;      // 8.4MB
  _Float16* h16     = (_Float16*)p;  p += (size_t)MROWS * DMODEL * 2;
  _Float16* win16   = (_Float16*)p;  p += (size_t)2 * DINNER * DMODEL * 2;
  _Float16* wout16  = (_Float16*)p;  p += (size_t)DMODEL * DINNER * 2;
  _Float16* wdt16   = (_Float16*)p;  p += (size_t)DINNER * DTRANK * 2;
  _Float16* wxp16   = (_Float16*)p;  p += (size_t)XPAD * DINNER * 2;
  _Float16* xdbl16  = (_Float16*)p;  p += (size_t)MROWS * DTRANK * 2;
  _Float16* y16     = (_Float16*)p;  p += (size_t)MROWS * DINNER * 2;
  float*    pbuf    = (float*)p;     p += (size_t)256 * NSEG * 256 * 4;
  float*    ebuf    = (float*)p;     p += (size_t)256 * NSEG * 256 * 4;
  // x_proj split-K partials alias delta16 (dead until dt GEMM writes it):
  float*    xp_part = (float*)delta16;   // 8 * 2048*128 * 4 = 8.4MB exactly

  // 0. all fp32->fp16 conversions in one launch
  f2h_all<<<(F2H_TOTAL + 255) / 256, 256, 0, stream>>>(
      hidden, in_proj_w, out_proj_w, dt_proj_w, x_proj_w,
      h16, win16, wout16, wdt16, wxp16);

  // 1. in_proj: xz16 = f16(hidden @ in_proj_w^T)  [2048, 4096], K=1024
  pgemm128<4><<<dim3(4096 / 128, MROWS / 128, 1), 256, 0, stream>>>(
      h16, DMODEL, win16, DMODEL, nullptr, 4096, DMODEL, xz16);

  // 2. x_proj with FUSED conv+SiLU A-staging: partials[z] = u @ x_proj_w^T
  //    chunk [2048,128], split-K=8  (no conv_silu kernel, no u16 buffer)
  pgemm64<0, true><<<dim3(1, MROWS / 64, XP_SPLIT), 256, 0, stream>>>(
      xz16, 2 * DINNER, wxp16, DINNER, xp_part, XPAD, DINNER,
      nullptr, nullptr, (size_t)MROWS * XPAD, conv_w, conv_b);

  // 2b. reduce partials -> xdbl32 + f16 dt cols
  reduce_xdbl<<<(MROWS * XPAD / 4) / 256, 256, 0, stream>>>(xp_part, xdbl32, xdbl16);

  // 3. dt: delta16 = f16(softplus(xdbl16 @ dt_proj_w^T + 2*b))  [2048,2048], K=64
  pgemm64<2, false><<<dim3(DINNER / 128, MROWS / 64, 1), 256, 0, stream>>>(
      xdbl16, DTRANK, wdt16, DTRANK, nullptr, DINNER, DTRANK,
      dt_proj_b, delta16, 0, nullptr, nullptr);

  // 4. selective scan, two-pass sequence-split (conv fused in staging) -> y16
  scan_part1<<<256 * NSEG, 256, 0, stream>>>(delta16, xz16, xdbl32, A_log,
                                             conv_w, conv_b, pbuf, ebuf);
  scan_part2<<<256 * NSEG, 256, 0, stream>>>(delta16, xz16, xdbl32, A_log, Dp,
                                             conv_w, conv_b, pbuf, ebuf, y16);

  // 5. out_proj: out = y @ out_proj_w^T [2048, 1024], K=2048 — 256 blocks
  pgemm64<0, false><<<dim3(DMODEL / 128, MROWS / 64, 1), 256, 0, stream>>>(
      y16, DINNER, wout16, DINNER, out, DMODEL, DINNER,
      nullptr, nullptr, 0, nullptr, nullptr);
}

// Round 13
// 241.207 us; speedup vs baseline: 1.0603x; 1.0603x over previous
//
#include <hip/hip_runtime.h>
#include <hip/hip_bf16.h>
#include <math.h>

#define BATCH   2
#define SEQLEN  1024
#define DMODEL  1024
#define DINNER  2048
#define DSTATE  16
#define DTRANK  64
#define XPAD    128             // padded x_dbl row stride (96 -> 128)
#define MROWS   (BATCH*SEQLEN)  // 2048
#define NSEG    8
#define SEGLEN  (SEQLEN/NSEG)   // 128
#define XP_SPLIT  8
#define OUT_SPLIT 2

typedef float    f32x4  __attribute__((ext_vector_type(4)));
typedef _Float16 f16x8  __attribute__((ext_vector_type(8)));
typedef _Float16 f16x4  __attribute__((ext_vector_type(4)));

// ---------------------------------------------------------------------------
// Pipelined fp16 MFMA GEMM, 64x128 tile, BK=64.
// Line-coalesced staging, reg-prefetch, LDS double-buffer, 1 barrier/iter.
// EPI 0: fp32 store (+zstride partials)  2: softplus(acc+2*bias) -> f16 C16
// ---------------------------------------------------------------------------
template<int EPI>
__global__ __launch_bounds__(256) void pgemm64(
    const _Float16* __restrict__ A, int lda,
    const _Float16* __restrict__ W, int ldw,
    float* __restrict__ C, int ldc, int K,
    const float* __restrict__ bias, _Float16* __restrict__ C16, size_t zstride)
{
  constexpr int APS = 520;    // A kb-plane stride (halves): 64*8 + 8 pad
  constexpr int BPS = 1032;   // B kb-plane stride: 128*8 + 8 pad
  __shared__ _Float16 As[2][8 * APS];
  __shared__ _Float16 Bs[2][8 * BPS];

  const int t  = threadIdx.x;
  const int m0 = blockIdx.y * 64, n0 = blockIdx.x * 128;
  const int kchunk = K / gridDim.z;
  const int kbeg = blockIdx.z * kchunk;
  const int nIter = kchunk / 64;

  const int kb = t & 7;
  const int r0 = t >> 3;
  const _Float16* gA = A + (size_t)(m0 + r0) * lda + kbeg + kb * 8;
  const _Float16* gB = W + (size_t)(n0 + r0) * ldw + kbeg + kb * 8;
  const size_t a32 = (size_t)32 * lda;
  const size_t b32 = (size_t)32 * ldw;
  const int aoff = kb * APS + r0 * 8;
  const int boff = kb * BPS + r0 * 8;

  {
    f16x8 a0 = *(const f16x8*)(gA);
    f16x8 a1 = *(const f16x8*)(gA + a32);
    f16x8 b0 = *(const f16x8*)(gB);
    f16x8 b1 = *(const f16x8*)(gB + b32);
    f16x8 b2 = *(const f16x8*)(gB + 2 * b32);
    f16x8 b3 = *(const f16x8*)(gB + 3 * b32);
    gA += 64; gB += 64;
    *(f16x8*)&As[0][aoff]       = a0;
    *(f16x8*)&As[0][aoff + 256] = a1;
    *(f16x8*)&Bs[0][boff]       = b0;
    *(f16x8*)&Bs[0][boff + 256] = b1;
    *(f16x8*)&Bs[0][boff + 512] = b2;
    *(f16x8*)&Bs[0][boff + 768] = b3;
  }

  const int lane = t & 63, wvi = t >> 6;
  const int wn = wvi * 32;
  const int lm = lane & 15, lk = lane >> 4;

  f32x4 acc[4][2] = {};

  for (int it = 0; it < nIter; ++it) {
    __syncthreads();
    const bool more = (it + 1 < nIter);
    f16x8 a0, a1, b0, b1, b2, b3;
    if (more) {
      a0 = *(const f16x8*)(gA);
      a1 = *(const f16x8*)(gA + a32);
      b0 = *(const f16x8*)(gB);
      b1 = *(const f16x8*)(gB + b32);
      b2 = *(const f16x8*)(gB + 2 * b32);
      b3 = *(const f16x8*)(gB + 3 * b32);
      gA += 64; gB += 64;
    }
    const int cb = it & 1;
#pragma unroll
    for (int s = 0; s < 2; ++s) {
      f16x8 av[4], bv[2];
#pragma unroll
      for (int i = 0; i < 4; ++i)
        av[i] = *(const f16x8*)&As[cb][(s * 4 + lk) * APS + (i * 16 + lm) * 8];
#pragma unroll
      for (int j = 0; j < 2; ++j)
        bv[j] = *(const f16x8*)&Bs[cb][(s * 4 + lk) * BPS + (wn + j * 16 + lm) * 8];
#pragma unroll
      for (int i = 0; i < 4; ++i)
#pragma unroll
        for (int j = 0; j < 2; ++j)
          acc[i][j] = __builtin_amdgcn_mfma_f32_16x16x32_f16(av[i], bv[j], acc[i][j], 0, 0, 0);
    }
    if (more) {
      const int nb = (it + 1) & 1;
      *(f16x8*)&As[nb][aoff]       = a0;
      *(f16x8*)&As[nb][aoff + 256] = a1;
      *(f16x8*)&Bs[nb][boff]       = b0;
      *(f16x8*)&Bs[nb][boff + 256] = b1;
      *(f16x8*)&Bs[nb][boff + 512] = b2;
      *(f16x8*)&Bs[nb][boff + 768] = b3;
    }
  }

  float* Cz = C + (size_t)blockIdx.z * zstride;
#pragma unroll
  for (int i = 0; i < 4; ++i) {
    const int mrow = m0 + i * 16 + lk * 4;
#pragma unroll
    for (int j = 0; j < 2; ++j) {
      const int col = n0 + wn + j * 16 + lm;
#pragma unroll
      for (int r = 0; r < 4; ++r) {
        float v = acc[i][j][r];
        size_t off = (size_t)(mrow + r) * ldc + col;
        if constexpr (EPI == 0) {
          Cz[off] = v;
        } else {  // EPI == 2: softplus -> f16
          float x = v + 2.f * bias[col];
          float sp = (x > 20.f) ? x : log1pf(__expf(x));
          C16[off] = (_Float16)sp;
        }
      }
    }
  }
}

// ---------------------------------------------------------------------------
// Pipelined fp16 MFMA GEMM, 128x128 tile, BK=64, 4 waves 2x2 (64x64/wave).
// EPI 0: fp32 store (+zstride)   4: f16 store
// ---------------------------------------------------------------------------
template<int EPI>
__global__ __launch_bounds__(256) void pgemm128(
    const _Float16* __restrict__ A, int lda,
    const _Float16* __restrict__ W, int ldw,
    float* __restrict__ C, int ldc, int K,
    _Float16* __restrict__ C16, size_t zstride)
{
  constexpr int PS = 1032;            // plane stride halves: 128*8 + 8 pad
  __shared__ _Float16 As[2][8 * PS];  // 33 KB
  __shared__ _Float16 Bs[2][8 * PS];  // 33 KB

  const int t  = threadIdx.x;
  const int m0 = blockIdx.y * 128, n0 = blockIdx.x * 128;
  const int kchunk = K / gridDim.z;
  const int kbeg = blockIdx.z * kchunk;
  const int nIter = kchunk / 64;

  const int kb = t & 7;
  const int r0 = t >> 3;
  const _Float16* gA = A + (size_t)(m0 + r0) * lda + kbeg + kb * 8;
  const _Float16* gB = W + (size_t)(n0 + r0) * ldw + kbeg + kb * 8;
  const size_t a32 = (size_t)32 * lda;
  const size_t b32 = (size_t)32 * ldw;
  const int soff = kb * PS + r0 * 8;

  {
    f16x8 ar[4], br[4];
#pragma unroll
    for (int j = 0; j < 4; ++j) {
      ar[j] = *(const f16x8*)(gA + j * a32);
      br[j] = *(const f16x8*)(gB + j * b32);
    }
    gA += 64; gB += 64;
#pragma unroll
    for (int j = 0; j < 4; ++j) {
      *(f16x8*)&As[0][soff + j * 256] = ar[j];
      *(f16x8*)&Bs[0][soff + j * 256] = br[j];
    }
  }

  const int lane = t & 63, wvi = t >> 6;
  const int wm = (wvi >> 1) * 64, wn = (wvi & 1) * 64;
  const int lm = lane & 15, lk = lane >> 4;

  f32x4 acc[4][4] = {};

  for (int it = 0; it < nIter; ++it) {
    __syncthreads();
    const bool more = (it + 1 < nIter);
    f16x8 ar[4], br[4];
    if (more) {
#pragma unroll
      for (int j = 0; j < 4; ++j) {
        ar[j] = *(const f16x8*)(gA + j * a32);
        br[j] = *(const f16x8*)(gB + j * b32);
      }
      gA += 64; gB += 64;
    }
    const int cb = it & 1;
#pragma unroll
    for (int s = 0; s < 2; ++s) {
      f16x8 av[4], bv[4];
#pragma unroll
      for (int i = 0; i < 4; ++i)
        av[i] = *(const f16x8*)&As[cb][(s * 4 + lk) * PS + (wm + i * 16 + lm) * 8];
#pragma unroll
      for (int j = 0; j < 4; ++j)
        bv[j] = *(const f16x8*)&Bs[cb][(s * 4 + lk) * PS + (wn + j * 16 + lm) * 8];
#pragma unroll
      for (int i = 0; i < 4; ++i)
#pragma unroll
        for (int j = 0; j < 4; ++j)
          acc[i][j] = __builtin_amdgcn_mfma_f32_16x16x32_f16(av[i], bv[j], acc[i][j], 0, 0, 0);
    }
    if (more) {
      const int nb = (it + 1) & 1;
#pragma unroll
      for (int j = 0; j < 4; ++j) {
        *(f16x8*)&As[nb][soff + j * 256] = ar[j];
        *(f16x8*)&Bs[nb][soff + j * 256] = br[j];
      }
    }
  }

  float* Cz = C + (size_t)blockIdx.z * zstride;
#pragma unroll
  for (int i = 0; i < 4; ++i) {
    const int mrow = m0 + wm + i * 16 + lk * 4;
#pragma unroll
    for (int j = 0; j < 4; ++j) {
      const int col = n0 + wn + j * 16 + lm;
#pragma unroll
      for (int r = 0; r < 4; ++r) {
        float v = acc[i][j][r];
        size_t off = (size_t)(mrow + r) * ldc + col;
        if constexpr (EPI == 0) {
          Cz[off] = v;
        } else {  // EPI == 4
          C16[off] = (_Float16)v;
        }
      }
    }
  }
}

// ---------------------------------------------------------------------------
// Fused fp32 -> fp16 conversion of all weights + hidden (one launch).
// ---------------------------------------------------------------------------
#define R0 (MROWS * DMODEL / 4)            // hidden:      524288
#define R1 (2 * DINNER * DMODEL / 4)       // in_proj_w:  1048576
#define R2 (DMODEL * DINNER / 4)           // out_proj_w:  524288
#define R3 (DINNER * DTRANK / 4)           // dt_proj_w:    32768
#define R4 (XPAD * DINNER / 4)             // x_proj_w pad: 65536
#define F2H_TOTAL (R0 + R1 + R2 + R3 + R4)

__global__ __launch_bounds__(256) void f2h_all(
    const float* __restrict__ hid, const float* __restrict__ w_in,
    const float* __restrict__ w_out, const float* __restrict__ w_dt,
    const float* __restrict__ w_xp,
    _Float16* __restrict__ hid16, _Float16* __restrict__ w_in16,
    _Float16* __restrict__ w_out16, _Float16* __restrict__ w_dt16,
    _Float16* __restrict__ w_xp16)
{
  int i = blockIdx.x * 256 + threadIdx.x;
  const float* src; _Float16* dst; int off;
  if (i < R0)                     { src = hid;   dst = hid16;   off = i; }
  else if (i < R0+R1)             { src = w_in;  dst = w_in16;  off = i - R0; }
  else if (i < R0+R1+R2)          { src = w_out; dst = w_out16; off = i - (R0+R1); }
  else if (i < R0+R1+R2+R3)       { src = w_dt;  dst = w_dt16;  off = i - (R0+R1+R2); }
  else if (i < F2H_TOTAL) {
    off = i - (R0+R1+R2+R3);
    int r = (off * 4) >> 11;                 // row of padded [128, 2048]
    f16x4 h = {0, 0, 0, 0};
    if (r < 96) {
      float4 v = ((const float4*)w_xp)[off];
      h = (f16x4){(_Float16)v.x, (_Float16)v.y, (_Float16)v.z, (_Float16)v.w};
    }
    ((f16x4*)w_xp16)[off] = h;
    return;
  } else return;
  float4 v = ((const float4*)src)[off];
  ((f16x4*)dst)[off] = (f16x4){(_Float16)v.x, (_Float16)v.y, (_Float16)v.z, (_Float16)v.w};
}

// ---------------------------------------------------------------------------
// Reduce x_proj split-K partials -> xdbl32 [2048,128] + f16 dt-cols [2048,64]
// ---------------------------------------------------------------------------
__global__ __launch_bounds__(256) void reduce_xdbl(
    const float* __restrict__ part,       // [XP_SPLIT][2048*128]
    float* __restrict__ xdbl32, _Float16* __restrict__ xdbl16)
{
  int i = blockIdx.x * 256 + threadIdx.x;          // float4 units, < 65536
  f32x4 s = ((const f32x4*)part)[i];
#pragma unroll
  for (int z = 1; z < XP_SPLIT; ++z)
    s += ((const f32x4*)part)[(size_t)z * (MROWS * XPAD / 4) + i];
  ((f32x4*)xdbl32)[i] = s;
  int col4 = (i & 31) * 4;
  if (col4 < DTRANK) {
    int row = i >> 5;
    *(f16x4*)&xdbl16[(size_t)row * DTRANK + col4] =
        (f16x4){(_Float16)s.x, (_Float16)s.y, (_Float16)s.z, (_Float16)s.w};
  }
}

// ---------------------------------------------------------------------------
// Reduce out_proj split-K partials -> out fp32
// ---------------------------------------------------------------------------
__global__ __launch_bounds__(256) void reduce_out(
    const float* __restrict__ part, float* __restrict__ out)
{
  int i = blockIdx.x * 256 + threadIdx.x;          // float4 units, < 524288
  f32x4 s = ((const f32x4*)part)[i];
#pragma unroll
  for (int z = 1; z < OUT_SPLIT; ++z)
    s += ((const f32x4*)part)[(size_t)z * (MROWS * DMODEL / 4) + i];
  ((f32x4*)out)[i] = s;
}

// ---------------------------------------------------------------------------
// Causal depthwise conv (k=4) + bias + SiLU; xz is f16; writes u16.
// ---------------------------------------------------------------------------
__global__ __launch_bounds__(256) void conv_silu(
    const _Float16* __restrict__ xz16,
    const float* __restrict__ conv_w,
    const float* __restrict__ conv_b,
    _Float16* __restrict__ u16)
{
  const int idx = blockIdx.x * 256 + threadIdx.x;  // row*DINNER + d
  const int d   = idx & (DINNER - 1);
  const int row = idx >> 11;
  const int l   = row & (SEQLEN - 1);
  float s = conv_b[d];
#pragma unroll
  for (int k = 0; k < 4; ++k) {
    int lt = l + k - 3;
    if (lt >= 0)
      s = fmaf((float)xz16[(size_t)(row + k - 3) * (2 * DINNER) + d],
               conv_w[d * 4 + k], s);
  }
  float v = s / (1.f + __expf(-s));
  u16[idx] = (_Float16)v;
}

// ---------------------------------------------------------------------------
// Selective scan, two-pass sequence-split (delta f16, u f16).
// ---------------------------------------------------------------------------
__device__ __forceinline__ float row_sum16(float x) {
  int v = __builtin_bit_cast(int, x);
  x += __builtin_bit_cast(float, __builtin_amdgcn_update_dpp(0, v, 0x128, 0xF, 0xF, true)); // row_ror:8
  v = __builtin_bit_cast(int, x);
  x += __builtin_bit_cast(float, __builtin_amdgcn_update_dpp(0, v, 0x124, 0xF, 0xF, true)); // row_ror:4
  v = __builtin_bit_cast(int, x);
  x += __builtin_bit_cast(float, __builtin_amdgcn_update_dpp(0, v, 0x4E, 0xF, 0xF, true));  // quad xor2
  v = __builtin_bit_cast(int, x);
  x += __builtin_bit_cast(float, __builtin_amdgcn_update_dpp(0, v, 0xB1, 0xF, 0xF, true));  // quad xor1
  return x;
}

__global__ __launch_bounds__(256) void scan_part1(
    const _Float16* __restrict__ delta16,
    const _Float16* __restrict__ u16,
    const float* __restrict__ x_dbl,
    const float* __restrict__ A_log,
    float* __restrict__ pbuf, float* __restrict__ ebuf)
{
  const int t = threadIdx.x;
  const int c = t >> 4, n = t & 15;
  const int bb = blockIdx.x;
  const int seg = bb >> 8;
  const int r = bb & 255;
  const int b = r >> 7;
  const int d_base = (r & 127) * 16;

  const float A_dn = -__expf(A_log[(d_base + c) * DSTATE + n]);
  float s = 0.f, p = 1.f;

  __shared__ __align__(16) float dl[16 * 68];
  __shared__ __align__(16) float ul[16 * 68];
  __shared__ __align__(16) float Bl[16 * 68];

  const int i_st = t >> 2;
  const int cc = (t & 3) * 4;

  for (int l0 = seg * SEGLEN; l0 < seg * SEGLEN + SEGLEN; l0 += 64) {
    const int row = b * SEQLEN + l0 + i_st;
    {
      f16x4  dh = *(const f16x4*)&delta16[(size_t)row * DINNER + d_base + cc];
      f16x4  uh = *(const f16x4*)&u16[(size_t)row * DINNER + d_base + cc];
      float4 Bv = *(const float4*)&x_dbl[(size_t)row * XPAD + DTRANK + cc];
      dl[(cc+0)*68 + i_st] = (float)dh[0]; dl[(cc+1)*68 + i_st] = (float)dh[1];
      dl[(cc+2)*68 + i_st] = (float)dh[2]; dl[(cc+3)*68 + i_st] = (float)dh[3];
      ul[(cc+0)*68 + i_st] = (float)uh[0]; ul[(cc+1)*68 + i_st] = (float)uh[1];
      ul[(cc+2)*68 + i_st] = (float)uh[2]; ul[(cc+3)*68 + i_st] = (float)uh[3];
      Bl[(cc+0)*68 + i_st] = Bv.x; Bl[(cc+1)*68 + i_st] = Bv.y;
      Bl[(cc+2)*68 + i_st] = Bv.z; Bl[(cc+3)*68 + i_st] = Bv.w;
    }
    __syncthreads();
#pragma unroll
    for (int i0 = 0; i0 < 64; i0 += 4) {
      f32x4 dv4 = *(const f32x4*)&dl[c * 68 + i0];
      f32x4 uv4 = *(const f32x4*)&ul[c * 68 + i0];
      f32x4 Bv4 = *(const f32x4*)&Bl[n * 68 + i0];
#pragma unroll
      for (int rr = 0; rr < 4; ++rr) {
        float dA = __expf(dv4[rr] * A_dn);
        s = fmaf(dA, s, dv4[rr] * Bv4[rr] * uv4[rr]);
        p *= dA;
      }
    }
    __syncthreads();
  }
  const int peIdx = (r * NSEG + seg) * 256 + t;
  pbuf[peIdx] = p;
  ebuf[peIdx] = s;
}

__global__ __launch_bounds__(256) void scan_part2(
    const _Float16* __restrict__ delta16,
    const _Float16* __restrict__ u16,
    const _Float16* __restrict__ xz16,   // z = xz16[:, DINNER:]
    const float* __restrict__ x_dbl,
    const float* __restrict__ A_log,
    const float* __restrict__ Dp,
    const float* __restrict__ pbuf,
    const float* __restrict__ ebuf,
    _Float16* __restrict__ y16)
{
  const int t = threadIdx.x;
  const int c = t >> 4, n = t & 15;
  const int bb = blockIdx.x;
  const int seg = bb >> 8;
  const int r = bb & 255;
  const int b = r >> 7;
  const int d_base = (r & 127) * 16;

  const float A_dn = -__expf(A_log[(d_base + c) * DSTATE + n]);

  float s = 0.f;
  {
    const int base = r * NSEG * 256 + t;
    for (int k = 0; k < seg; ++k)
      s = fmaf(pbuf[base + k * 256], s, ebuf[base + k * 256]);
  }

  __shared__ __align__(16) float dl[16 * 68];
  __shared__ __align__(16) float ul[16 * 68];
  __shared__ __align__(16) float Bl[16 * 68];
  __shared__ __align__(16) float Cl[16 * 68];
  __shared__ __align__(16) float yl[16 * 68];
  __shared__ __align__(16) float z_s[64 * 16];
  __shared__ float Dp_s[16];

  if (t < 16) Dp_s[t] = Dp[d_base + t];

  const int i_st = t >> 2;
  const int cc = (t & 3) * 4;

  for (int l0 = seg * SEGLEN; l0 < seg * SEGLEN + SEGLEN; l0 += 64) {
    const int row = b * SEQLEN + l0 + i_st;
    {
      f16x4  dh = *(const f16x4*)&delta16[(size_t)row * DINNER + d_base + cc];
      f16x4  uh = *(const f16x4*)&u16[(size_t)row * DINNER + d_base + cc];
      float4 Bv = *(const float4*)&x_dbl[(size_t)row * XPAD + DTRANK + cc];
      float4 Cv = *(const float4*)&x_dbl[(size_t)row * XPAD + DTRANK + DSTATE + cc];
      f16x4  zh = *(const f16x4*)&xz16[(size_t)row * (2 * DINNER) + DINNER + d_base + cc];
      dl[(cc+0)*68 + i_st] = (float)dh[0]; dl[(cc+1)*68 + i_st] = (float)dh[1];
      dl[(cc+2)*68 + i_st] = (float)dh[2]; dl[(cc+3)*68 + i_st] = (float)dh[3];
      ul[(cc+0)*68 + i_st] = (float)uh[0]; ul[(cc+1)*68 + i_st] = (float)uh[1];
      ul[(cc+2)*68 + i_st] = (float)uh[2]; ul[(cc+3)*68 + i_st] = (float)uh[3];
      Bl[(cc+0)*68 + i_st] = Bv.x; Bl[(cc+1)*68 + i_st] = Bv.y;
      Bl[(cc+2)*68 + i_st] = Bv.z; Bl[(cc+3)*68 + i_st] = Bv.w;
      Cl[(cc+0)*68 + i_st] = Cv.x; Cl[(cc+1)*68 + i_st] = Cv.y;
      Cl[(cc+2)*68 + i_st] = Cv.z; Cl[(cc+3)*68 + i_st] = Cv.w;
      float4 zv = make_float4((float)zh[0], (float)zh[1], (float)zh[2], (float)zh[3]);
      *(float4*)&z_s[t * 4] = zv;
    }
    __syncthreads();

#pragma unroll
    for (int i0 = 0; i0 < 64; i0 += 4) {
      f32x4 dv4 = *(const f32x4*)&dl[c * 68 + i0];
      f32x4 uv4 = *(const f32x4*)&ul[c * 68 + i0];
      f32x4 Bv4 = *(const f32x4*)&Bl[n * 68 + i0];
      f32x4 Cv4 = *(const f32x4*)&Cl[n * 68 + i0];
      f32x4 py;
#pragma unroll
      for (int rr = 0; rr < 4; ++rr) {
        float dA = __expf(dv4[rr] * A_dn);
        s = fmaf(dA, s, dv4[rr] * Bv4[rr] * uv4[rr]);
        py[rr] = row_sum16(s * Cv4[rr]);
      }
      if (n == 0) *(f32x4*)&yl[c * 68 + i0] = py;
    }
    __syncthreads();

#pragma unroll
    for (int k = 0; k < 4; ++k) {
      int o = t + 256 * k;
      int i = o >> 4, c2 = o & 15;
      float ssum = yl[c2 * 68 + i];
      float uv = ul[c2 * 68 + i];
      float zv = z_s[o];
      float yv = fmaf(uv, Dp_s[c2], ssum);
      yv *= zv / (1.f + __expf(-zv));
      y16[(size_t)(b * SEQLEN + l0 + i) * DINNER + d_base + c2] = (_Float16)yv;
    }
    __syncthreads();
  }
}

// ---------------------------------------------------------------------------
extern "C" void kernel_launch(void* const* d_in, const int* in_sizes, int n_in,
                              void* d_out, int out_size, void* d_ws, size_t ws_size,
                              hipStream_t stream)
{
  const float* hidden     = (const float*)d_in[0];
  const float* in_proj_w  = (const float*)d_in[1];
  const float* conv_w     = (const float*)d_in[2];
  const float* conv_b     = (const float*)d_in[3];
  const float* x_proj_w   = (const float*)d_in[4];
  const float* dt_proj_w  = (const float*)d_in[5];
  const float* dt_proj_b  = (const float*)d_in[6];
  const float* A_log      = (const float*)d_in[7];
  const float* Dp         = (const float*)d_in[8];
  const float* out_proj_w = (const float*)d_in[9];
  float* out = (float*)d_out;

  char* p = (char*)d_ws;
  _Float16* xz16    = (_Float16*)p;  p += (size_t)MROWS * 2 * DINNER * 2;  // 16.8MB
  _Float16* u16     = (_Float16*)p;  p += (size_t)MROWS * DINNER * 2;      // 8.4MB
  float*    xdbl32  = (float*)p;     p += (size_t)MROWS * XPAD * 4;        // 1.05MB
  _Float16* delta16 = (_Float16*)p;  p += (size_t)MROWS * DINNER * 2;      // 8.4MB
  _Float16* h16     = (_Float16*)p;  p += (size_t)MROWS * DMODEL * 2;
  _Float16* win16   = (_Float16*)p;  p += (size_t)2 * DINNER * DMODEL * 2;
  _Float16* wout16  = (_Float16*)p;  p += (size_t)DMODEL * DINNER * 2;
  _Float16* wdt16   = (_Float16*)p;  p += (size_t)DINNER * DTRANK * 2;
  _Float16* wxp16   = (_Float16*)p;  p += (size_t)XPAD * DINNER * 2;
  _Float16* xdbl16  = (_Float16*)p;  p += (size_t)MROWS * DTRANK * 2;
  _Float16* y16     = (_Float16*)p;  p += (size_t)MROWS * DINNER * 2;
  float*    pbuf    = (float*)p;     p += (size_t)256 * NSEG * 256 * 4;
  float*    ebuf    = (float*)p;     p += (size_t)256 * NSEG * 256 * 4;
  // lifetime-aliased partial buffers:
  float*    xp_part  = (float*)delta16;  // 8 * 2048*128 * 4 = 8.4MB (delta dead until dt)
  float*    out_part = (float*)xz16;     // 2 * 2048*1024 * 4 (xz dead after scan2)

  // 0. all fp32->fp16 conversions in one launch
  f2h_all<<<(F2H_TOTAL + 255) / 256, 256, 0, stream>>>(
      hidden, in_proj_w, out_proj_w, dt_proj_w, x_proj_w,
      h16, win16, wout16, wdt16, wxp16);

  // 1. in_proj: xz16 = f16(hidden @ in_proj_w^T)  [2048, 4096], K=1024
  pgemm128<4><<<dim3(4096 / 128, MROWS / 128, 1), 256, 0, stream>>>(
      h16, DMODEL, win16, DMODEL, nullptr, 4096, DMODEL, xz16, 0);

  // 2. conv + SiLU -> u16
  conv_silu<<<(MROWS * DINNER) / 256, 256, 0, stream>>>(xz16, conv_w, conv_b, u16);

  // 3. x_proj: partials[z] = u @ x_proj_w^T chunk  [2048,128], split-K=8
  pgemm64<0><<<dim3(1, MROWS / 64, XP_SPLIT), 256, 0, stream>>>(
      u16, DINNER, wxp16, DINNER, xp_part, XPAD, DINNER, nullptr, nullptr,
      (size_t)MROWS * XPAD);

  // 3b. reduce partials -> xdbl32 + f16 dt cols
  reduce_xdbl<<<(MROWS * XPAD / 4) / 256, 256, 0, stream>>>(xp_part, xdbl32, xdbl16);

  // 4. dt: delta16 = f16(softplus(xdbl16 @ dt_proj_w^T + 2*b))  [2048,2048], K=64
  pgemm64<2><<<dim3(DINNER / 128, MROWS / 64, 1), 256, 0, stream>>>(
      xdbl16, DTRANK, wdt16, DTRANK, nullptr, DINNER, DTRANK, dt_proj_b, delta16, 0);

  // 5. selective scan, two-pass sequence-split -> y16
  scan_part1<<<256 * NSEG, 256, 0, stream>>>(delta16, u16, xdbl32, A_log, pbuf, ebuf);
  scan_part2<<<256 * NSEG, 256, 0, stream>>>(delta16, u16, xz16, xdbl32, A_log, Dp,
                                             pbuf, ebuf, y16);

  // 6. out_proj: partials[z] = y @ out_proj_w^T chunk [2048,1024], split-K=2
  pgemm128<0><<<dim3(DMODEL / 128, MROWS / 128, OUT_SPLIT), 256, 0, stream>>>(
      y16, DINNER, wout16, DINNER, out_part, DMODEL, DINNER, nullptr,
      (size_t)MROWS * DMODEL);

  // 6b. reduce -> out
  reduce_out<<<(MROWS * DMODEL / 4) / 256, 256, 0, stream>>>(out_part, out);
}